// Round 16
// baseline (468.758 us; speedup 1.0000x reference)
//
#include <hip/hip_runtime.h>
#include <hip/hip_fp16.h>
#include <stdint.h>

static constexpr int N_USERS = 1000000;
static constexpr int N_ITEMS = 200000;
static constexpr int N_EDGES = 25000000;

// Tile/partition geometry
static constexpr int TILE   = 16384;                 // edges per LDS-sorted tile
static constexpr int NTILES = 3;
static constexpr int CHUNK  = TILE * NTILES;         // 49152 edges per block
static constexpr int NBLK   = (N_EDGES + CHUNK - 1) / CHUNK;   // 509
static constexpr int RUNS   = NBLK * NTILES;         // runs per bucket = 1527

static constexpr int SHIFT_U = 11;                   // users: 2048 bins/bucket
static constexpr int SHIFT_I = 9;                    // items:  512 bins/bucket
static constexpr int NB_U = (N_USERS + (1 << SHIFT_U) - 1) >> SHIFT_U;  // 489
static constexpr int NB_I = (N_ITEMS + (1 << SHIFT_I) - 1) >> SHIFT_I;  // 391

// Fixed-point scale for u32 LDS accumulation (integer LDS atomics are
// full-rate; ds_add_f32 measured ~4cy/lane -- confirmed round 13: 750->516us).
static constexpr float FPSCALE  = 32768.0f;          // 2^15
static constexpr float FPINV    = 1.0f / 32768.0f;

typedef float    f4 __attribute__((ext_vector_type(4)));
typedef int      i4 __attribute__((ext_vector_type(4)));
typedef uint32_t u4 __attribute__((ext_vector_type(4)));

// ---------------------------------------------------------------------------
// P1: per-block tile-sorted partition. Round-13 structure, but metadata is
// written DIRECTLY TRANSPOSED (startsT[b][run], scattered 4B stores into the
// L2-resident 3MB table) -- kills the separate k_transpose pass entirely.
// ---------------------------------------------------------------------------
template<int SHIFT, int NB>
__global__ __launch_bounds__(1024) void k_part(const float* __restrict__ w,
                                               const int* __restrict__ r,
                                               uint32_t* __restrict__ payload,
                                               uint32_t* __restrict__ startsT) {
    __shared__ uint32_t stage[TILE];     // 64 KB
    __shared__ uint32_t hist[1024];      // histogram, then write cursors
    __shared__ uint32_t wsum[16];
    const int blk = blockIdx.x;
    const int t = threadIdx.x;
    const int lane = t & 63, wave = t >> 6;
    const int begin = blk * CHUNK;
    const int bend = (begin + CHUNK < N_EDGES) ? begin + CHUNK : N_EDGES;
    const uint32_t lmask = (1u << SHIFT) - 1u;

    for (int tile = 0; tile < NTILES; ++tile) {
        const int tb = begin + tile * TILE;
        int n = bend - tb;
        n = n < 0 ? 0 : (n > TILE ? TILE : n);
        const int n4 = n >> 2;                       // all boundaries %4 == 0
        const int rb = blk * NTILES + tile;          // run index

        hist[t] = 0;
        __syncthreads();

        // 1) load r+w, build payload in regs, histogram
        uint32_t idx[16];
        uint32_t pay[16];
        #pragma unroll
        for (int k = 0; k < 4; ++k) {
            int v = t + k * 1024;
            if (v < n4) {
                i4 u = __builtin_nontemporal_load((const i4*)r + (tb >> 2) + v);
                f4 a = __builtin_nontemporal_load((const f4*)w + (tb >> 2) + v);
                idx[4 * k + 0] = (uint32_t)u.x;
                idx[4 * k + 1] = (uint32_t)u.y;
                idx[4 * k + 2] = (uint32_t)u.z;
                idx[4 * k + 3] = (uint32_t)u.w;
                pay[4 * k + 0] = (__float_as_uint(__expf(a.x)) & ~lmask) | ((uint32_t)u.x & lmask);
                pay[4 * k + 1] = (__float_as_uint(__expf(a.y)) & ~lmask) | ((uint32_t)u.y & lmask);
                pay[4 * k + 2] = (__float_as_uint(__expf(a.z)) & ~lmask) | ((uint32_t)u.z & lmask);
                pay[4 * k + 3] = (__float_as_uint(__expf(a.w)) & ~lmask) | ((uint32_t)u.w & lmask);
                atomicAdd(&hist[(uint32_t)u.x >> SHIFT], 1u);
                atomicAdd(&hist[(uint32_t)u.y >> SHIFT], 1u);
                atomicAdd(&hist[(uint32_t)u.z >> SHIFT], 1u);
                atomicAdd(&hist[(uint32_t)u.w >> SHIFT], 1u);
            }
        }
        __syncthreads();

        // 2) exclusive scan of hist[0..1023] (entries >= NB are zero)
        uint32_t c = hist[t];
        uint32_t x = c;
        #pragma unroll
        for (int d = 1; d < 64; d <<= 1) {
            uint32_t y = __shfl_up(x, d);
            if (lane >= d) x += y;
        }
        if (lane == 63) wsum[wave] = x;
        __syncthreads();
        if (t < 16) {
            uint32_t y = wsum[t];
            uint32_t s = y;
            #pragma unroll
            for (int d = 1; d < 16; d <<= 1) {
                uint32_t z = __shfl_up(s, d, 16);
                if (t >= d) s += z;
            }
            wsum[t] = s - y;                         // exclusive wave prefix
        }
        __syncthreads();
        uint32_t excl = x - c + wsum[wave];

        // transposed metadata write (scattered 4B, L2-resident 3MB table)
        if (t < NB) startsT[(size_t)t * RUNS + rb] = (uint32_t)tb + excl;
        if (t == 0) startsT[(size_t)NB * RUNS + rb] = (uint32_t)(tb + n);  // sentinel
        hist[t] = excl;                              // tile-local cursors
        __syncthreads();

        // 3) scatter into LDS stage (registers only)
        #pragma unroll
        for (int k = 0; k < 4; ++k) {
            int v = t + k * 1024;
            if (v < n4) {
                uint32_t p0 = atomicAdd(&hist[idx[4 * k + 0] >> SHIFT], 1u);
                stage[p0] = pay[4 * k + 0];
                uint32_t p1 = atomicAdd(&hist[idx[4 * k + 1] >> SHIFT], 1u);
                stage[p1] = pay[4 * k + 1];
                uint32_t p2 = atomicAdd(&hist[idx[4 * k + 2] >> SHIFT], 1u);
                stage[p2] = pay[4 * k + 2];
                uint32_t p3 = atomicAdd(&hist[idx[4 * k + 3] >> SHIFT], 1u);
                stage[p3] = pay[4 * k + 3];
            }
        }
        __syncthreads();

        // 4) coalesced dump of the sorted tile
        #pragma unroll
        for (int k = 0; k < 4; ++k) {
            int v = t + k * 1024;
            if (v < n4) {
                u4 s4 = ((const u4*)stage)[v];
                __builtin_nontemporal_store(s4, (u4*)payload + (tb >> 2) + v);
            }
        }
        __syncthreads();                             // before next tile's hist[]=0
    }
}

// ---------------------------------------------------------------------------
// P2: one block per bucket with u32 fixed-point LDS atomics (round 13).
// ---------------------------------------------------------------------------
template<int SHIFT, int NB>
__global__ __launch_bounds__(1024) void k_bucket(const uint32_t* __restrict__ payload,
                                                 const uint32_t* __restrict__ startsT, // [NB+1][RUNS]
                                                 int nelems,
                                                 const float* __restrict__ w0,   // null for items
                                                 __half* __restrict__ recip,
                                                 float* __restrict__ lfw0) {     // null for items
    constexpr int BINS = 1 << SHIFT;
    constexpr int KMAX = (RUNS + 127) / 128;         // 12
    __shared__ uint32_t binsU[BINS];
    __shared__ uint32_t srow[RUNS];
    __shared__ uint32_t erow[RUNS];
    const int b = blockIdx.x;
    const int t = threadIdx.x;
    for (int i = t; i < BINS; i += 1024) binsU[i] = 0u;
    const uint32_t* s0 = startsT + (size_t)b * RUNS;
    const uint32_t* e0 = startsT + (size_t)(b + 1) * RUNS;
    for (int i = t; i < RUNS; i += 1024) {
        srow[i] = s0[i];
        erow[i] = e0[i];
    }
    __syncthreads();

    const int sub = t >> 3, sl = t & 7;              // 128 subgroups of 8 lanes

    uint32_t sk[KMAX], ek[KMAX];
    #pragma unroll
    for (int k = 0; k < KMAX; ++k) {
        int run = sub + (k << 7);
        bool ok = run < RUNS;
        sk[k] = ok ? srow[run] : 0u;
        ek[k] = ok ? erow[run] : 0u;
    }

    const u4* payload4 = (const u4*)payload;
    #pragma unroll
    for (int k = 0; k < KMAX; ++k) {
        uint32_t s = sk[k], e = ek[k];
        uint32_t j  = (s >> 2) + sl;
        uint32_t j1 = (e + 3) >> 2;
        bool have = j < j1;
        u4 cur;
        if (have) cur = __builtin_nontemporal_load(&payload4[j]);
        while (have) {
            uint32_t jn = j + 8;
            bool haveN = jn < j1;
            u4 nxt;
            if (haveN) nxt = __builtin_nontemporal_load(&payload4[jn]); // in flight
            uint32_t g = j << 2;
            #pragma unroll
            for (int c = 0; c < 4; ++c) {
                uint32_t gg = g + c;
                if (gg >= s && gg < e) {
                    uint32_t p = cur[c];
                    float ev = __uint_as_float(p & ~(uint32_t)(BINS - 1));
                    atomicAdd(&binsU[p & (BINS - 1)],
                              (uint32_t)(ev * FPSCALE + 0.5f));
                }
            }
            j = jn;
            cur = nxt;
            have = haveN;
        }
    }
    __syncthreads();

    for (int i = t; i < BINS; i += 1024) {
        int g = b * BINS + i;
        if (g < nelems) {
            float s = (float)binsU[i] * FPINV;
            if (w0) {
                float e = __expf(w0[g]);
                s += e;
                lfw0[g] = e / s;
            }
            recip[g] = __float2half(1.0f / s);
        }
    }
}

// ---------------------------------------------------------------------------
// Per-edge finalize, BOTH relations fused, x2 unroll, TRUE DEPTH 16:
// all 8 coalesced vectors (4 index + 4 stream) issue first, then all 16
// gathers back-to-back -- in-order vmcnt never forces an intermediate
// gather drain (the round-5/15 order drained the 8 user gathers before the
// item gathers issued: true depth was only 8). sched_barrier(0) pins the
// schedule. Est ~60 VGPR -- below the 64 occupancy cliff.
// ---------------------------------------------------------------------------
__global__ __launch_bounds__(256) void k_edges(const f4* __restrict__ w1,
                                               const f4* __restrict__ w2,
                                               const i4* __restrict__ r1,
                                               const i4* __restrict__ r2,
                                               const __half* __restrict__ recip1,
                                               const __half* __restrict__ recip2,
                                               f4* __restrict__ lfw1,
                                               f4* __restrict__ lfw2) {
    const int nv2 = N_EDGES / 8;                     // 3,125,000 (exact)
    int tid = blockIdx.x * blockDim.x + threadIdx.x;
    int stride = gridDim.x * blockDim.x;
    for (int v2 = tid; v2 < nv2; v2 += stride) {
        int v = v2 * 2;
        // Phase A: all 8 independent coalesced loads
        i4 u0  = __builtin_nontemporal_load(&r1[v]);
        i4 u1  = __builtin_nontemporal_load(&r1[v + 1]);
        i4 it0 = __builtin_nontemporal_load(&r2[v]);
        i4 it1 = __builtin_nontemporal_load(&r2[v + 1]);
        f4 a0  = __builtin_nontemporal_load(&w1[v]);
        f4 a1  = __builtin_nontemporal_load(&w1[v + 1]);
        f4 b0  = __builtin_nontemporal_load(&w2[v]);
        f4 b1  = __builtin_nontemporal_load(&w2[v + 1]);
        // Phase B: all 16 gathers in flight together (waits only on u*/it*)
        float g0 = __half2float(recip1[u0.x]);
        float g1 = __half2float(recip1[u0.y]);
        float g2 = __half2float(recip1[u0.z]);
        float g3 = __half2float(recip1[u0.w]);
        float g4 = __half2float(recip1[u1.x]);
        float g5 = __half2float(recip1[u1.y]);
        float g6 = __half2float(recip1[u1.z]);
        float g7 = __half2float(recip1[u1.w]);
        float h0 = __half2float(recip2[it0.x]);
        float h1 = __half2float(recip2[it0.y]);
        float h2 = __half2float(recip2[it0.z]);
        float h3 = __half2float(recip2[it0.w]);
        float h4 = __half2float(recip2[it1.x]);
        float h5 = __half2float(recip2[it1.y]);
        float h6 = __half2float(recip2[it1.z]);
        float h7 = __half2float(recip2[it1.w]);
        __builtin_amdgcn_sched_barrier(0);
        // Phase C: consume
        f4 o0, o1;
        o0.x = __expf(a0.x) * g0;
        o0.y = __expf(a0.y) * g1;
        o0.z = __expf(a0.z) * g2;
        o0.w = __expf(a0.w) * g3;
        o1.x = __expf(a1.x) * g4;
        o1.y = __expf(a1.y) * g5;
        o1.z = __expf(a1.z) * g6;
        o1.w = __expf(a1.w) * g7;
        __builtin_nontemporal_store(o0, &lfw1[v]);
        __builtin_nontemporal_store(o1, &lfw1[v + 1]);

        f4 p0, p1;
        p0.x = __expf(b0.x) * h0;
        p0.y = __expf(b0.y) * h1;
        p0.z = __expf(b0.z) * h2;
        p0.w = __expf(b0.w) * h3;
        p1.x = __expf(b1.x) * h4;
        p1.y = __expf(b1.y) * h5;
        p1.z = __expf(b1.z) * h6;
        p1.w = __expf(b1.w) * h7;
        __builtin_nontemporal_store(p0, &lfw2[v]);
        __builtin_nontemporal_store(p1, &lfw2[v + 1]);
    }
}

extern "C" void kernel_launch(void* const* d_in, const int* in_sizes, int n_in,
                              void* d_out, int out_size, void* d_ws, size_t ws_size,
                              hipStream_t stream) {
    const float* w0 = (const float*)d_in[0];
    const float* w1 = (const float*)d_in[1];
    const float* w2 = (const float*)d_in[2];
    const int* r1 = (const int*)d_in[3];
    const int* r2 = (const int*)d_in[4];

    float* out = (float*)d_out;
    float* lfw0 = out;                        // [N_USERS]
    float* lfw1 = out + N_USERS;              // [N_EDGES]
    float* lfw2 = out + N_USERS + N_EDGES;    // [N_EDGES]

    // Scratch payload (100 MB) lives in the lfw1/lfw2 region (200 MB): it is
    // fully consumed by k_bucket before k_edges overwrites it.
    uint32_t* payload = (uint32_t*)(out + N_USERS);

    float* ws = (float*)d_ws;
    __half* recip1 = (__half*)ws;                       // [N_USERS]  (2 MB)
    __half* recip2 = recip1 + N_USERS;                  // [N_ITEMS]  (0.4 MB)
    uint32_t* startsT = (uint32_t*)(recip2 + N_ITEMS);  // [(NB_U+1)*RUNS] ~3 MB

    // Relation 1 (users)
    k_part<SHIFT_U, NB_U><<<NBLK, 1024, 0, stream>>>(w1, r1, payload, startsT);
    k_bucket<SHIFT_U, NB_U><<<NB_U, 1024, 0, stream>>>(payload, startsT,
                                                       N_USERS, w0, recip1, lfw0);

    // Relation 2 (items) — reuses payload/startsT
    k_part<SHIFT_I, NB_I><<<NBLK, 1024, 0, stream>>>(w2, r2, payload, startsT);
    k_bucket<SHIFT_I, NB_I><<<NB_I, 1024, 0, stream>>>(payload, startsT,
                                                       N_ITEMS, nullptr, recip2, nullptr);

    // Fused per-edge finalize (payload fully consumed; safe to overwrite lfw1)
    k_edges<<<2048, 256, 0, stream>>>((const f4*)w1, (const f4*)w2,
                                      (const i4*)r1, (const i4*)r2,
                                      recip1, recip2,
                                      (f4*)lfw1, (f4*)lfw2);
}

// Round 17
// 457.250 us; speedup vs baseline: 1.0252x; 1.0252x over previous
//
#include <hip/hip_runtime.h>
#include <hip/hip_fp16.h>
#include <stdint.h>

static constexpr int N_USERS = 1000000;
static constexpr int N_ITEMS = 200000;
static constexpr int N_EDGES = 25000000;

// Tile/partition geometry
static constexpr int TILE   = 16384;                 // edges per LDS-sorted tile
static constexpr int NTILES = 3;
static constexpr int CHUNK  = TILE * NTILES;         // 49152 edges per block
static constexpr int NBLK   = (N_EDGES + CHUNK - 1) / CHUNK;   // 509
static constexpr int RUNS   = NBLK * NTILES;         // runs per bucket = 1527

static constexpr int SHIFT_U = 11;                   // users: 2048 bins/bucket
static constexpr int SHIFT_I = 9;                    // items:  512 bins/bucket
static constexpr int NB_U = (N_USERS + (1 << SHIFT_U) - 1) >> SHIFT_U;  // 489
static constexpr int NB_I = (N_ITEMS + (1 << SHIFT_I) - 1) >> SHIFT_I;  // 391

// Fixed-point scale for u32 LDS accumulation (integer LDS atomics are
// full-rate; ds_add_f32 measured ~4cy/lane -- confirmed round 13: 750->516us).
static constexpr float FPSCALE  = 32768.0f;          // 2^15
static constexpr float FPINV    = 1.0f / 32768.0f;

typedef float    f4 __attribute__((ext_vector_type(4)));
typedef int      i4 __attribute__((ext_vector_type(4)));
typedef uint32_t u4 __attribute__((ext_vector_type(4)));

// ---------------------------------------------------------------------------
// P1: per-block tile-sorted partition; metadata written directly transposed
// (startsT[b][run], scattered 4B stores into the L2-resident ~3MB table).
// ---------------------------------------------------------------------------
template<int SHIFT, int NB>
__global__ __launch_bounds__(1024) void k_part(const float* __restrict__ w,
                                               const int* __restrict__ r,
                                               uint32_t* __restrict__ payload,
                                               uint32_t* __restrict__ startsT) {
    __shared__ uint32_t stage[TILE];     // 64 KB
    __shared__ uint32_t hist[1024];      // histogram, then write cursors
    __shared__ uint32_t wsum[16];
    const int blk = blockIdx.x;
    const int t = threadIdx.x;
    const int lane = t & 63, wave = t >> 6;
    const int begin = blk * CHUNK;
    const int bend = (begin + CHUNK < N_EDGES) ? begin + CHUNK : N_EDGES;
    const uint32_t lmask = (1u << SHIFT) - 1u;

    for (int tile = 0; tile < NTILES; ++tile) {
        const int tb = begin + tile * TILE;
        int n = bend - tb;
        n = n < 0 ? 0 : (n > TILE ? TILE : n);
        const int n4 = n >> 2;                       // all boundaries %4 == 0
        const int rb = blk * NTILES + tile;          // run index

        hist[t] = 0;
        __syncthreads();

        // 1) load r+w, build payload in regs, histogram
        uint32_t idx[16];
        uint32_t pay[16];
        #pragma unroll
        for (int k = 0; k < 4; ++k) {
            int v = t + k * 1024;
            if (v < n4) {
                i4 u = __builtin_nontemporal_load((const i4*)r + (tb >> 2) + v);
                f4 a = __builtin_nontemporal_load((const f4*)w + (tb >> 2) + v);
                idx[4 * k + 0] = (uint32_t)u.x;
                idx[4 * k + 1] = (uint32_t)u.y;
                idx[4 * k + 2] = (uint32_t)u.z;
                idx[4 * k + 3] = (uint32_t)u.w;
                pay[4 * k + 0] = (__float_as_uint(__expf(a.x)) & ~lmask) | ((uint32_t)u.x & lmask);
                pay[4 * k + 1] = (__float_as_uint(__expf(a.y)) & ~lmask) | ((uint32_t)u.y & lmask);
                pay[4 * k + 2] = (__float_as_uint(__expf(a.z)) & ~lmask) | ((uint32_t)u.z & lmask);
                pay[4 * k + 3] = (__float_as_uint(__expf(a.w)) & ~lmask) | ((uint32_t)u.w & lmask);
                atomicAdd(&hist[(uint32_t)u.x >> SHIFT], 1u);
                atomicAdd(&hist[(uint32_t)u.y >> SHIFT], 1u);
                atomicAdd(&hist[(uint32_t)u.z >> SHIFT], 1u);
                atomicAdd(&hist[(uint32_t)u.w >> SHIFT], 1u);
            }
        }
        __syncthreads();

        // 2) exclusive scan of hist[0..1023] (entries >= NB are zero)
        uint32_t c = hist[t];
        uint32_t x = c;
        #pragma unroll
        for (int d = 1; d < 64; d <<= 1) {
            uint32_t y = __shfl_up(x, d);
            if (lane >= d) x += y;
        }
        if (lane == 63) wsum[wave] = x;
        __syncthreads();
        if (t < 16) {
            uint32_t y = wsum[t];
            uint32_t s = y;
            #pragma unroll
            for (int d = 1; d < 16; d <<= 1) {
                uint32_t z = __shfl_up(s, d, 16);
                if (t >= d) s += z;
            }
            wsum[t] = s - y;                         // exclusive wave prefix
        }
        __syncthreads();
        uint32_t excl = x - c + wsum[wave];

        // transposed metadata write (scattered 4B, L2-resident table)
        if (t < NB) startsT[(size_t)t * RUNS + rb] = (uint32_t)tb + excl;
        if (t == 0) startsT[(size_t)NB * RUNS + rb] = (uint32_t)(tb + n);  // sentinel
        hist[t] = excl;                              // tile-local cursors
        __syncthreads();

        // 3) scatter into LDS stage (registers only)
        #pragma unroll
        for (int k = 0; k < 4; ++k) {
            int v = t + k * 1024;
            if (v < n4) {
                uint32_t p0 = atomicAdd(&hist[idx[4 * k + 0] >> SHIFT], 1u);
                stage[p0] = pay[4 * k + 0];
                uint32_t p1 = atomicAdd(&hist[idx[4 * k + 1] >> SHIFT], 1u);
                stage[p1] = pay[4 * k + 1];
                uint32_t p2 = atomicAdd(&hist[idx[4 * k + 2] >> SHIFT], 1u);
                stage[p2] = pay[4 * k + 2];
                uint32_t p3 = atomicAdd(&hist[idx[4 * k + 3] >> SHIFT], 1u);
                stage[p3] = pay[4 * k + 3];
            }
        }
        __syncthreads();

        // 4) coalesced dump of the sorted tile
        #pragma unroll
        for (int k = 0; k < 4; ++k) {
            int v = t + k * 1024;
            if (v < n4) {
                u4 s4 = ((const u4*)stage)[v];
                __builtin_nontemporal_store(s4, (u4*)payload + (tb >> 2) + v);
            }
        }
        __syncthreads();                             // before next tile's hist[]=0
    }
}

// ---------------------------------------------------------------------------
// P2: one block per bucket with u32 fixed-point LDS atomics (round 13).
// ---------------------------------------------------------------------------
template<int SHIFT, int NB>
__global__ __launch_bounds__(1024) void k_bucket(const uint32_t* __restrict__ payload,
                                                 const uint32_t* __restrict__ startsT, // [NB+1][RUNS]
                                                 int nelems,
                                                 const float* __restrict__ w0,   // null for items
                                                 __half* __restrict__ recip,
                                                 float* __restrict__ lfw0) {     // null for items
    constexpr int BINS = 1 << SHIFT;
    constexpr int KMAX = (RUNS + 127) / 128;         // 12
    __shared__ uint32_t binsU[BINS];
    __shared__ uint32_t srow[RUNS];
    __shared__ uint32_t erow[RUNS];
    const int b = blockIdx.x;
    const int t = threadIdx.x;
    for (int i = t; i < BINS; i += 1024) binsU[i] = 0u;
    const uint32_t* s0 = startsT + (size_t)b * RUNS;
    const uint32_t* e0 = startsT + (size_t)(b + 1) * RUNS;
    for (int i = t; i < RUNS; i += 1024) {
        srow[i] = s0[i];
        erow[i] = e0[i];
    }
    __syncthreads();

    const int sub = t >> 3, sl = t & 7;              // 128 subgroups of 8 lanes

    uint32_t sk[KMAX], ek[KMAX];
    #pragma unroll
    for (int k = 0; k < KMAX; ++k) {
        int run = sub + (k << 7);
        bool ok = run < RUNS;
        sk[k] = ok ? srow[run] : 0u;
        ek[k] = ok ? erow[run] : 0u;
    }

    const u4* payload4 = (const u4*)payload;
    #pragma unroll
    for (int k = 0; k < KMAX; ++k) {
        uint32_t s = sk[k], e = ek[k];
        uint32_t j  = (s >> 2) + sl;
        uint32_t j1 = (e + 3) >> 2;
        bool have = j < j1;
        u4 cur;
        if (have) cur = __builtin_nontemporal_load(&payload4[j]);
        while (have) {
            uint32_t jn = j + 8;
            bool haveN = jn < j1;
            u4 nxt;
            if (haveN) nxt = __builtin_nontemporal_load(&payload4[jn]); // in flight
            uint32_t g = j << 2;
            #pragma unroll
            for (int c = 0; c < 4; ++c) {
                uint32_t gg = g + c;
                if (gg >= s && gg < e) {
                    uint32_t p = cur[c];
                    float ev = __uint_as_float(p & ~(uint32_t)(BINS - 1));
                    atomicAdd(&binsU[p & (BINS - 1)],
                              (uint32_t)(ev * FPSCALE + 0.5f));
                }
            }
            j = jn;
            cur = nxt;
            have = haveN;
        }
    }
    __syncthreads();

    for (int i = t; i < BINS; i += 1024) {
        int g = b * BINS + i;
        if (g < nelems) {
            float s = (float)binsU[i] * FPINV;
            if (w0) {
                float e = __expf(w0[g]);
                s += e;
                lfw0[g] = e / s;
            }
            recip[g] = __float2half(1.0f / s);
        }
    }
}

// ---------------------------------------------------------------------------
// Per-edge finalize, BOTH relations fused, x2 unroll -- ROUND-15 ORDER
// VERBATIM (measured 264us; the "depth 16" reorder of round 16 regressed to
// 275us: compiler re-interleaved despite sched_barrier, VGPR 32->28).
//   lfw1 = exp(w1) * recip1[r1];  lfw2 = exp(w2) * recip2[r2]
// ---------------------------------------------------------------------------
__global__ __launch_bounds__(256) void k_edges(const f4* __restrict__ w1,
                                               const f4* __restrict__ w2,
                                               const i4* __restrict__ r1,
                                               const i4* __restrict__ r2,
                                               const __half* __restrict__ recip1,
                                               const __half* __restrict__ recip2,
                                               f4* __restrict__ lfw1,
                                               f4* __restrict__ lfw2) {
    const int nv2 = N_EDGES / 8;                     // 3,125,000 (exact)
    int tid = blockIdx.x * blockDim.x + threadIdx.x;
    int stride = gridDim.x * blockDim.x;
    for (int v2 = tid; v2 < nv2; v2 += stride) {
        int v = v2 * 2;
        // users relation, 8 edges
        i4 u0 = __builtin_nontemporal_load(&r1[v]);
        i4 u1 = __builtin_nontemporal_load(&r1[v + 1]);
        f4 a0 = __builtin_nontemporal_load(&w1[v]);
        f4 a1 = __builtin_nontemporal_load(&w1[v + 1]);
        float g0 = __half2float(recip1[u0.x]);
        float g1 = __half2float(recip1[u0.y]);
        float g2 = __half2float(recip1[u0.z]);
        float g3 = __half2float(recip1[u0.w]);
        float g4 = __half2float(recip1[u1.x]);
        float g5 = __half2float(recip1[u1.y]);
        float g6 = __half2float(recip1[u1.z]);
        float g7 = __half2float(recip1[u1.w]);
        // items relation, 8 edges
        i4 it0 = __builtin_nontemporal_load(&r2[v]);
        i4 it1 = __builtin_nontemporal_load(&r2[v + 1]);
        f4 b0 = __builtin_nontemporal_load(&w2[v]);
        f4 b1 = __builtin_nontemporal_load(&w2[v + 1]);
        float h0 = __half2float(recip2[it0.x]);
        float h1 = __half2float(recip2[it0.y]);
        float h2 = __half2float(recip2[it0.z]);
        float h3 = __half2float(recip2[it0.w]);
        float h4 = __half2float(recip2[it1.x]);
        float h5 = __half2float(recip2[it1.y]);
        float h6 = __half2float(recip2[it1.z]);
        float h7 = __half2float(recip2[it1.w]);

        f4 o0, o1;
        o0.x = __expf(a0.x) * g0;
        o0.y = __expf(a0.y) * g1;
        o0.z = __expf(a0.z) * g2;
        o0.w = __expf(a0.w) * g3;
        o1.x = __expf(a1.x) * g4;
        o1.y = __expf(a1.y) * g5;
        o1.z = __expf(a1.z) * g6;
        o1.w = __expf(a1.w) * g7;
        __builtin_nontemporal_store(o0, &lfw1[v]);
        __builtin_nontemporal_store(o1, &lfw1[v + 1]);

        f4 p0, p1;
        p0.x = __expf(b0.x) * h0;
        p0.y = __expf(b0.y) * h1;
        p0.z = __expf(b0.z) * h2;
        p0.w = __expf(b0.w) * h3;
        p1.x = __expf(b1.x) * h4;
        p1.y = __expf(b1.y) * h5;
        p1.z = __expf(b1.z) * h6;
        p1.w = __expf(b1.w) * h7;
        __builtin_nontemporal_store(p0, &lfw2[v]);
        __builtin_nontemporal_store(p1, &lfw2[v + 1]);
    }
}

extern "C" void kernel_launch(void* const* d_in, const int* in_sizes, int n_in,
                              void* d_out, int out_size, void* d_ws, size_t ws_size,
                              hipStream_t stream) {
    const float* w0 = (const float*)d_in[0];
    const float* w1 = (const float*)d_in[1];
    const float* w2 = (const float*)d_in[2];
    const int* r1 = (const int*)d_in[3];
    const int* r2 = (const int*)d_in[4];

    float* out = (float*)d_out;
    float* lfw0 = out;                        // [N_USERS]
    float* lfw1 = out + N_USERS;              // [N_EDGES]
    float* lfw2 = out + N_USERS + N_EDGES;    // [N_EDGES]

    // Scratch payload (100 MB) lives in the lfw1/lfw2 region (200 MB): it is
    // fully consumed by k_bucket before k_edges overwrites it.
    uint32_t* payload = (uint32_t*)(out + N_USERS);

    float* ws = (float*)d_ws;
    __half* recip1 = (__half*)ws;                       // [N_USERS]  (2 MB)
    __half* recip2 = recip1 + N_USERS;                  // [N_ITEMS]  (0.4 MB)
    uint32_t* startsT = (uint32_t*)(recip2 + N_ITEMS);  // [(NB_U+1)*RUNS] ~3 MB

    // Relation 1 (users)
    k_part<SHIFT_U, NB_U><<<NBLK, 1024, 0, stream>>>(w1, r1, payload, startsT);
    k_bucket<SHIFT_U, NB_U><<<NB_U, 1024, 0, stream>>>(payload, startsT,
                                                       N_USERS, w0, recip1, lfw0);

    // Relation 2 (items) — reuses payload/startsT
    k_part<SHIFT_I, NB_I><<<NBLK, 1024, 0, stream>>>(w2, r2, payload, startsT);
    k_bucket<SHIFT_I, NB_I><<<NB_I, 1024, 0, stream>>>(payload, startsT,
                                                       N_ITEMS, nullptr, recip2, nullptr);

    // Fused per-edge finalize (payload fully consumed; safe to overwrite lfw1)
    k_edges<<<2048, 256, 0, stream>>>((const f4*)w1, (const f4*)w2,
                                      (const i4*)r1, (const i4*)r2,
                                      recip1, recip2,
                                      (f4*)lfw1, (f4*)lfw2);
}